// Round 12
// baseline (719.090 us; speedup 1.0000x reference)
//
#include <hip/hip_runtime.h>
#include <math.h>

// ---------------- constants ----------------
#define T_STEPS 50
#define NB 512
#define RS2 0.70710678118654752f
#define INV_SQRT_L 0.40824829046386302f
#define WPACK_SHORT_OFF 36864    // d_ws offset in shorts (= float off 18432)

struct SchedArg { float cx0[T_STEPS], cxt[T_STEPS], sig[T_STEPS], s1m[T_STEPS], isab[T_STEPS]; };
struct FreqArg  { double f[64]; };

typedef short bf16x8 __attribute__((ext_vector_type(8)));
typedef float f32x4  __attribute__((ext_vector_type(4)));

__device__ __forceinline__ float4 ld4s(const float* p) { return *reinterpret_cast<const float4*>(p); }
__device__ __forceinline__ float4 ld4g(const float* __restrict__ p) { return *reinterpret_cast<const float4*>(p); }
__device__ __forceinline__ float fast_sig(float x)  { return 1.f / (1.f + __expf(-x)); }
__device__ __forceinline__ float fast_tanh(float x) { float e = __expf(2.f * x); return 1.f - 2.f / (e + 1.f); }

// f32 -> bf16 (RNE). Prep kernel uses the manual version; hot path uses HW packer.
__device__ __forceinline__ unsigned rne1(float f) {
    unsigned u = __float_as_uint(f);
    return (u + 0x7FFFu + ((u >> 16) & 1u)) >> 16;
}
__device__ __forceinline__ unsigned pk2(float a, float b) {   // lo=bf16(a), hi=bf16(b)
    unsigned r;
    asm("v_cvt_pk_bf16_f32 %0, %1, %2" : "=v"(r) : "v"(a), "v"(b));
    return r;
}
__device__ __forceinline__ void st_bf4(short* p, float a, float b, float c, float d) {
    uint2 v; v.x = pk2(a, b); v.y = pk2(c, d);
    *reinterpret_cast<uint2*>(p) = v;
}
__device__ __forceinline__ f32x4 mma(bf16x8 a, bf16x8 b, f32x4 c) {
    return __builtin_amdgcn_mfma_f32_16x16x32_bf16(a, b, c, 0, 0, 0);
}
__device__ __forceinline__ f32x4 bias4s(const float* p) {
    float4 b = ld4s(p);
    f32x4 r; r[0] = b.x; r[1] = b.y; r[2] = b.z; r[3] = b.w;
    return r;
}
__device__ __forceinline__ bf16x8 ldfrag(const short* p) {
    return *reinterpret_cast<const bf16x8*>(p);
}

// ---------------- kernel A: Student-t marginal fit ----------------
__global__ __launch_bounds__(256) void fit_kernel(const float* __restrict__ xh,
                                                  float* __restrict__ loc,
                                                  float* __restrict__ scalef) {
    int gid = blockIdx.x * 256 + threadIdx.x;
    int b = gid >> 7, d = gid & 127;
    const float* p = xh + (size_t)b * 192 * 128 + d;
    float s = 0.f;
    for (int t = 0; t < 192; ++t) s += p[t * 128];
    float m = s * (1.0f / 192.0f);
    float v = 0.f;
    for (int t = 0; t < 192; ++t) {
        float c = p[t * 128] - m; c *= c;
        v = (t == 0) ? c : 0.94f * v + (1.0f - 0.94f) * c;
    }
    loc[gid] = m;
    scalef[gid] = fmaxf(sqrtf(v * 0.5f), 1e-5f);
}

// ---------------- kernel B: per-t embedding -> cond[6][32] ----------------
__global__ __launch_bounds__(256) void temb_kernel(
    const float* __restrict__ w1, const float* __restrict__ b1,
    const float* __restrict__ w2, const float* __restrict__ b2,
    const float* __restrict__ wt, const float* __restrict__ bt,
    float* __restrict__ cond_all, FreqArg fq) {
    int t = blockIdx.x;
    int tid = threadIdx.x;
    __shared__ float pe[128], te1[512], te2[512];
    if (tid < 64) {
        double e = (double)t * fq.f[tid];
        pe[tid]      = (float)sin(e);
        pe[tid + 64] = (float)cos(e);
    }
    __syncthreads();
    for (int j = tid; j < 512; j += 256) {
        float acc = b1[j];
        for (int k = 0; k < 128; ++k) acc += pe[k] * w1[k * 512 + j];
        te1[j] = acc / (1.f + expf(-acc));
    }
    __syncthreads();
    for (int j = tid; j < 512; j += 256) {
        float acc = b2[j];
        for (int k = 0; k < 512; ++k) acc += te1[k] * w2[k * 512 + j];
        te2[j] = acc / (1.f + expf(-acc));
    }
    __syncthreads();
    if (tid < 192) {
        int l = tid >> 5, c = tid & 31;
        float acc = bt[l * 32 + c];
        const float* w = wt + (size_t)l * 512 * 32 + c;
        for (int k = 0; k < 512; ++k) acc += te2[k] * w[k * 32];
        cond_all[t * 192 + tid] = acc;
    }
}

// ---------------- kernel P: pack weights as bf16 A-fragments ----------------
// A-frag layout (v_mfma_f32_16x16x32_bf16): lane l elem j holds A[m=l&15][k=(l>>4)*8+j].
__global__ __launch_bounds__(256) void prep_kernel(
    const float* __restrict__ w_in, const float* __restrict__ lyr_wdil,
    const float* __restrict__ lyr_wout, const float* __restrict__ w_o1,
    const float* __restrict__ w_o2, short* __restrict__ wpack) {
    int gid = blockIdx.x * 256 + threadIdx.x;
    if (gid >= 58368) return;
    int j = gid & 7, l = (gid >> 3) & 63, frag = gid >> 9;
    int m = l & 15, k = (l >> 4) * 8 + j;
    float v;
    if (frag < 8) {
        int m2 = frag >> 2, ks = frag & 3;
        v = w_in[(m2 * 16 + m) * 128 + ks * 32 + k];
    } else if (frag < 80) {
        int fi = frag - 8;
        int li = fi / 12, rem = fi % 12;
        int mg = rem / 6, rem2 = rem % 6;
        int tp = rem2 >> 1, gf = rem2 & 1;
        int o = gf * 32 + mg * 16 + m;
        v = lyr_wdil[((li * 64 + o) * 32 + k) * 3 + tp];
    } else if (frag < 104) {
        int fi = frag - 80;
        int li = fi >> 2, mo = fi & 3;
        v = lyr_wout[li * 2048 + (mo * 16 + m) * 32 + k];
    } else if (frag < 106) {
        int m2 = frag - 104;
        v = w_o1[(m2 * 16 + m) * 32 + k] * INV_SQRT_L;
    } else {
        int m8 = frag - 106;
        v = w_o2[(m8 * 16 + m) * 32 + k];
    }
    wpack[gid] = (short)rne1(v);
}

// ---------------- kernel C: 50-step diffusion (MFMA), 2 rows/block, 4 waves ----------------
// In-wave dual-row ILP: every phase executes row 0 then row 1 in the same
// wave's stream (independent chains -> guaranteed overlap). A-frags shared
// across rows; per-row state (x, h, skip) in registers. grid 256, 1 block/CU.
__global__ __launch_bounds__(256, 1) void diffusion_kernel(
    const float* __restrict__ z_init, const float* __restrict__ noise,
    const float* __restrict__ b_in,  const float* __restrict__ lyr_bdil,
    const float* __restrict__ lyr_bout, const float* __restrict__ b_o1,
    const float* __restrict__ b_o2, const float* __restrict__ cond_all,
    const short* __restrict__ wpack, const float* __restrict__ loc,
    const float* __restrict__ scalef, float* __restrict__ out, SchedArg sc) {

    __shared__ __align__(16) short xbB[2][32 * 136];  // x bf16 [col][128k]; cols 24..31 zero
    __shared__ __align__(16) short hcB[2][33 * 40];   // h+cond; col 32 = zeros
    __shared__ __align__(16) short actB[2][32 * 40];  // conv act / s
    __shared__ __align__(16) short skB[2][32 * 40];   // skip publish buffer
    __shared__ __align__(16) float biasB[960];        // b_in|bdil|bout|b_o1|b_o2
    __shared__ __align__(16) float condB[2][192];     // double-buffered cond[t]

    const int tid = threadIdx.x;
    const int wv  = __builtin_amdgcn_readfirstlane(tid >> 6);   // 0..3
    const int l   = tid & 63;
    const int ln  = l & 15;
    const int lq  = l >> 4;
    const int bb  = blockIdx.x;          // rows 2bb, 2bb+1

    const short* wpP1 = wpack;
    const short* wpCv = wpack + 4096;
    const short* wpWo = wpack + 40960;
    const short* wpO1 = wpack + 53248;
    const short* wpO2 = wpack + 54272;

    const int mh   = wv >> 1;            // m-tile for P1/conv/res/sk/o1
    const int nn   = wv & 1;             // n-tile
    const int colw = nn * 16 + ln;       // 0..31 (valid h < 24)

    // ---- hoisted step-invariant A-frags (shared across both rows) ----
    bf16x8 aP1[4], aCv[6][3][2], aO1, aWoR[5], aWoS[6], aO2[2];
#pragma unroll
    for (int ks = 0; ks < 4; ++ks)
        aP1[ks] = ldfrag(wpP1 + (mh * 4 + ks) * 512 + l * 8);
    aO1 = ldfrag(wpO1 + mh * 512 + l * 8);
#pragma unroll
    for (int li = 0; li < 6; ++li) {
#pragma unroll
        for (int tp = 0; tp < 3; ++tp) {
            if (li == 5 && tp != 1) continue;
#pragma unroll
            for (int gf = 0; gf < 2; ++gf)
                aCv[li][tp][gf] = ldfrag(wpCv + (li * 12 + mh * 6 + tp * 2 + gf) * 512 + l * 8);
        }
        if (li < 5) aWoR[li] = ldfrag(wpWo + (li * 4 + mh) * 512 + l * 8);
        aWoS[li] = ldfrag(wpWo + (li * 4 + 2 + mh) * 512 + l * 8);
    }
    aO2[0] = ldfrag(wpO2 + wv * 512 + l * 8);
    aO2[1] = ldfrag(wpO2 + (wv + 4) * 512 + l * 8);

    // ---- init LDS + x registers (both rows) ----
#pragma unroll
    for (int r = 0; r < 2; ++r) {
        const float* zg = z_init + (size_t)(bb * 2 + r) * 3072;
        for (int i = tid; i < 3072; i += 256) {
            int d = i / 24, h = i - d * 24;
            xbB[r][h * 136 + d] = (short)rne1(zg[i]);
        }
        for (int i = tid; i < 1088; i += 256) xbB[r][24 * 136 + i] = 0;
        if (tid < 40) hcB[r][32 * 40 + tid] = 0;
    }
    for (int i = tid; i < 960; i += 256) {
        float v;
        if      (i < 32)  v = b_in[i];
        else if (i < 416) v = lyr_bdil[i - 32];
        else if (i < 800) v = lyr_bout[i - 416];
        else if (i < 832) v = b_o1[i - 800];
        else              v = b_o2[i - 832];
        biasB[i] = v;
    }
    if (tid < 192) condB[0][tid] = cond_all[(T_STEPS - 1) * 192 + tid];

    f32x4 xr[2][2][2];                   // [row][mi][n]
#pragma unroll
    for (int r = 0; r < 2; ++r)
#pragma unroll
        for (int mi = 0; mi < 2; ++mi)
#pragma unroll
            for (int n = 0; n < 2; ++n) {
                const int col = n * 16 + ln;
                const int d0 = (wv + 4 * mi) * 16 + lq * 4;
#pragma unroll
                for (int i = 0; i < 4; ++i)
                    xr[r][mi][n][i] = (col < 24)
                        ? z_init[(size_t)(bb * 2 + r) * 3072 + (d0 + i) * 24 + col] : 0.f;
            }
    __syncthreads();

    for (int step = 0; step < T_STEPS; ++step) {
        const int t = T_STEPS - 1 - step;
        const float* cnd = condB[step & 1];

        float cndnext = 0.f;
        if (step + 1 < T_STEPS && tid < 192)
            cndnext = cond_all[(t - 1) * 192 + tid];

        // ======== P1 (both rows): h = relu(Win @ x + b_in) -> hr + hcB ========
        f32x4 hr[2], skr[2];
        {
            f32x4 bia = bias4s(biasB + mh * 16 + lq * 4);
            float4 cv = ld4s(cnd + mh * 16 + lq * 4);
#pragma unroll
            for (int r = 0; r < 2; ++r) {
                f32x4 acc = bia;
                const short* xb = xbB[r] + colw * 136;
#pragma unroll
                for (int ks = 0; ks < 4; ++ks)
                    acc = mma(aP1[ks], ldfrag(xb + ks * 32 + lq * 8), acc);
#pragma unroll
                for (int i = 0; i < 4; ++i) acc[i] = fmaxf(acc[i], 0.f);
                hr[r] = acc;
#pragma unroll
                for (int i = 0; i < 4; ++i) skr[r][i] = 0.f;
                st_bf4(hcB[r] + colw * 40 + mh * 16 + lq * 4,
                       acc[0] + cv.x, acc[1] + cv.y, acc[2] + cv.z, acc[3] + cv.w);
            }
        }
        __syncthreads();

        // ======== 6 residual layers ========
#pragma unroll
        for (int li = 0; li < 6; ++li) {
            const int dd = 1 << li;
            // ---- conv + gated act -> actB (both rows) ----
            {
                f32x4 bg = bias4s(biasB + 32 + li * 64 + mh * 16 + lq * 4);
                f32x4 bf = bias4s(biasB + 32 + li * 64 + 32 + mh * 16 + lq * 4);
#pragma unroll
                for (int r = 0; r < 2; ++r) {
                    f32x4 accg = bg, accf = bf;
#pragma unroll
                    for (int tp = 0; tp < 3; ++tp) {
                        if (li == 5 && tp != 1) continue;
                        int hh = colw + (tp - 1) * dd;
                        int colp = ((unsigned)hh < 24u) ? hh : 32;
                        bf16x8 b = ldfrag(hcB[r] + colp * 40 + lq * 8);
                        accg = mma(aCv[li][tp][0], b, accg);
                        accf = mma(aCv[li][tp][1], b, accf);
                    }
                    st_bf4(actB[r] + colw * 40 + mh * 16 + lq * 4,
                           fast_tanh(accf[0]) * fast_sig(accg[0]),
                           fast_tanh(accf[1]) * fast_sig(accg[1]),
                           fast_tanh(accf[2]) * fast_sig(accg[2]),
                           fast_tanh(accf[3]) * fast_sig(accg[3]));
                }
            }
            __syncthreads();

            // ---- wout: res -> hr + hcB; sk -> skr; publish skB at l5 (both rows) ----
            {
                f32x4 bR, bS;
                if (li < 5) bR = bias4s(biasB + 416 + li * 64 + mh * 16 + lq * 4);
                bS = bias4s(biasB + 416 + li * 64 + (2 + mh) * 16 + lq * 4);
                float4 cv;
                if (li < 5) cv = ld4s(cnd + (li + 1) * 32 + mh * 16 + lq * 4);
#pragma unroll
                for (int r = 0; r < 2; ++r) {
                    bf16x8 b = ldfrag(actB[r] + colw * 40 + lq * 8);
                    if (li < 5) {
                        f32x4 accR = mma(aWoR[li], b, bR);
#pragma unroll
                        for (int i = 0; i < 4; ++i) hr[r][i] = (hr[r][i] + accR[i]) * RS2;
                        st_bf4(hcB[r] + colw * 40 + mh * 16 + lq * 4,
                               hr[r][0] + cv.x, hr[r][1] + cv.y,
                               hr[r][2] + cv.z, hr[r][3] + cv.w);
                    }
                    f32x4 accS = mma(aWoS[li], b, bS);
#pragma unroll
                    for (int i = 0; i < 4; ++i) skr[r][i] += accS[i];
                    if (li == 5)
                        st_bf4(skB[r] + colw * 40 + mh * 16 + lq * 4,
                               skr[r][0], skr[r][1], skr[r][2], skr[r][3]);
                }
            }
            __syncthreads();
        }

        // ======== o1 (both rows): s = relu(b_o1 + Wo1s @ skip) -> actB ========
        {
            f32x4 bia = bias4s(biasB + 800 + mh * 16 + lq * 4);
#pragma unroll
            for (int r = 0; r < 2; ++r) {
                f32x4 acc = mma(aO1, ldfrag(skB[r] + colw * 40 + lq * 8), bia);
                st_bf4(actB[r] + colw * 40 + mh * 16 + lq * 4,
                       fmaxf(acc[0], 0.f), fmaxf(acc[1], 0.f),
                       fmaxf(acc[2], 0.f), fmaxf(acc[3], 0.f));
            }
        }
        __syncthreads();

        // ======== o2 (both rows): eps + fused DDPM x-update; publish cond ========
        {
            const float cx0 = sc.cx0[t], cxt = sc.cxt[t], sig = sc.sig[t];
            const float s1m = sc.s1m[t], isab = sc.isab[t];
#pragma unroll
            for (int r = 0; r < 2; ++r) {
                const float* nzb = noise + ((size_t)step * NB + bb * 2 + r) * 3072;
#pragma unroll
                for (int mi = 0; mi < 2; ++mi) {
                    const int d0 = (wv + 4 * mi) * 16 + lq * 4;
                    f32x4 bia = bias4s(biasB + 832 + d0);
#pragma unroll
                    for (int n = 0; n < 2; ++n) {
                        const int col = n * 16 + ln;
                        f32x4 acc = mma(aO2[mi], ldfrag(actB[r] + col * 40 + lq * 8), bia);
                        if (col < 24) {
                            const float* nzp = nzb + col;
                            float xn[4];
#pragma unroll
                            for (int i = 0; i < 4; ++i) {
                                float xv = xr[r][mi][n][i];
                                float nz = nzp[(d0 + i) * 24];
                                float x0 = fminf(fmaxf((xv - s1m * acc[i]) * isab, -1.f), 1.f);
                                xn[i] = cx0 * x0 + cxt * xv + sig * nz;
                                xr[r][mi][n][i] = xn[i];
                            }
                            st_bf4(xbB[r] + col * 136 + d0, xn[0], xn[1], xn[2], xn[3]);
                        }
                    }
                }
            }
            if (step + 1 < T_STEPS && tid < 192)
                condB[(step + 1) & 1][tid] = cndnext;
        }
        __syncthreads();
    }

    // ---- epilogue: Gaussian -> Student-t4 from registers, direct stores ----
#pragma unroll
    for (int r = 0; r < 2; ++r) {
        const int b = (bb * 2 + r) & 31;
#pragma unroll
        for (int mi = 0; mi < 2; ++mi) {
#pragma unroll
            for (int n = 0; n < 2; ++n) {
                const int col = n * 16 + ln;
                if (col >= 24) continue;
                const int d0 = (wv + 4 * mi) * 16 + lq * 4;
                float4 l4 = ld4g(loc + b * 128 + d0);
                float4 s4 = ld4g(scalef + b * 128 + d0);
                float4 o4;
#pragma unroll
                for (int e = 0; e < 4; ++e) {
                    float z = xr[r][mi][n][e];
                    float u = 0.5f * (1.f + erff(z * RS2));
                    u = fminf(fmaxf(u, 1e-6f), 1.f - 1e-6f);
                    float a4 = fminf(fmaxf(4.f * u * (1.f - u), 1e-12f), 1.f);
                    float rr = sqrtf(a4);
                    float q2 = 2.f * sqrtf(fmaxf(cosf(acosf(rr) * (1.f / 3.f)) / rr - 1.f, 0.f));
                    float tstd = (u < 0.5f) ? -q2 : q2;
                    (&o4.x)[e] = (&l4.x)[e] + (&s4.x)[e] * tstd;
                }
                *reinterpret_cast<float4*>(out + (size_t)(bb * 2 + r) * 3072 + col * 128 + d0) = o4;
            }
        }
    }
}

// ---------------- host ----------------
extern "C" void kernel_launch(void* const* d_in, const int* in_sizes, int n_in,
                              void* d_out, int out_size, void* d_ws, size_t ws_size,
                              hipStream_t stream) {
    const float* x_hist  = (const float*)d_in[0];
    const float* z_init  = (const float*)d_in[1];
    const float* noise   = (const float*)d_in[2];
    const float* w_in    = (const float*)d_in[3];
    const float* b_in    = (const float*)d_in[4];
    const float* temb_w1 = (const float*)d_in[5];
    const float* temb_b1 = (const float*)d_in[6];
    const float* temb_w2 = (const float*)d_in[7];
    const float* temb_b2 = (const float*)d_in[8];
    const float* lyr_wt  = (const float*)d_in[9];
    const float* lyr_bt  = (const float*)d_in[10];
    const float* lyr_wdil= (const float*)d_in[11];
    const float* lyr_bdil= (const float*)d_in[12];
    const float* lyr_wout= (const float*)d_in[13];
    const float* lyr_bout= (const float*)d_in[14];
    const float* w_o1    = (const float*)d_in[15];
    const float* b_o1    = (const float*)d_in[16];
    const float* w_o2    = (const float*)d_in[17];
    const float* b_o2    = (const float*)d_in[18];
    float* out = (float*)d_out;

    float* loc      = (float*)d_ws;                     // 4096 f32
    float* scalef   = loc + 4096;                       // 4096 f32
    float* cond_all = scalef + 4096;                    // 9600 f32
    short* wpack    = (short*)d_ws + WPACK_SHORT_OFF;   // 58368 bf16

    SchedArg sa;
    double abar = 1.0;
    for (int t = 0; t < T_STEPS; ++t) {
        double beta  = 1e-4 + (0.1 - 1e-4) * ((double)t / 49.0);
        double alpha = 1.0 - beta;
        double abprev = abar;
        abar *= alpha;
        sa.cx0[t]  = (float)(beta * sqrt(abprev) / (1.0 - abar));
        sa.cxt[t]  = (float)((1.0 - abprev) * sqrt(alpha) / (1.0 - abar));
        double pv  = beta * (1.0 - abprev) / (1.0 - abar);
        sa.sig[t]  = (t > 0) ? (float)sqrt(pv) : 0.f;
        sa.s1m[t]  = (float)sqrt(1.0 - abar);
        sa.isab[t] = (float)(1.0 / sqrt(abar));
    }
    FreqArg fa;
    for (int j = 0; j < 64; ++j) fa.f[j] = pow(10.0, (double)j * 4.0 / 63.0);

    prep_kernel<<<228, 256, 0, stream>>>(w_in, lyr_wdil, lyr_wout, w_o1, w_o2, wpack);
    fit_kernel<<<16, 256, 0, stream>>>(x_hist, loc, scalef);
    temb_kernel<<<T_STEPS, 256, 0, stream>>>(temb_w1, temb_b1, temb_w2, temb_b2,
                                             lyr_wt, lyr_bt, cond_all, fa);
    diffusion_kernel<<<256, 256, 0, stream>>>(z_init, noise, b_in, lyr_bdil,
                                              lyr_bout, b_o1, b_o2, cond_all,
                                              wpack, loc, scalef, out, sa);
}

// Round 13
// 673.927 us; speedup vs baseline: 1.0670x; 1.0670x over previous
//
#include <hip/hip_runtime.h>
#include <math.h>

// ---------------- constants ----------------
#define T_STEPS 50
#define NB 512
#define RS2 0.70710678118654752f
#define INV_SQRT_L 0.40824829046386302f
#define WPACK_SHORT_OFF 36864    // d_ws offset in shorts (= float off 18432)

struct SchedArg { float cx0[T_STEPS], cxt[T_STEPS], sig[T_STEPS], s1m[T_STEPS], isab[T_STEPS]; };
struct FreqArg  { double f[64]; };

typedef short bf16x8 __attribute__((ext_vector_type(8)));
typedef float f32x4  __attribute__((ext_vector_type(4)));

__device__ __forceinline__ float4 ld4s(const float* p) { return *reinterpret_cast<const float4*>(p); }
__device__ __forceinline__ float4 ld4g(const float* __restrict__ p) { return *reinterpret_cast<const float4*>(p); }
__device__ __forceinline__ float fast_sig(float x)  { return 1.f / (1.f + __expf(-x)); }
__device__ __forceinline__ float fast_tanh(float x) { float e = __expf(2.f * x); return 1.f - 2.f / (e + 1.f); }

__device__ __forceinline__ unsigned rne1(float f) {
    unsigned u = __float_as_uint(f);
    return (u + 0x7FFFu + ((u >> 16) & 1u)) >> 16;
}
__device__ __forceinline__ unsigned pk2(float a, float b) {   // lo=bf16(a), hi=bf16(b)
    unsigned r;
    asm("v_cvt_pk_bf16_f32 %0, %1, %2" : "=v"(r) : "v"(a), "v"(b));
    return r;
}
__device__ __forceinline__ void st_bf4(short* p, float a, float b, float c, float d) {
    uint2 v; v.x = pk2(a, b); v.y = pk2(c, d);
    *reinterpret_cast<uint2*>(p) = v;
}
__device__ __forceinline__ f32x4 mma(bf16x8 a, bf16x8 b, f32x4 c) {
    return __builtin_amdgcn_mfma_f32_16x16x32_bf16(a, b, c, 0, 0, 0);
}
__device__ __forceinline__ f32x4 bias4s(const float* p) {
    float4 b = ld4s(p);
    f32x4 r; r[0] = b.x; r[1] = b.y; r[2] = b.z; r[3] = b.w;
    return r;
}
__device__ __forceinline__ bf16x8 ldfrag(const short* p) {
    return *reinterpret_cast<const bf16x8*>(p);
}

// ---------------- kernel A: Student-t marginal fit ----------------
__global__ __launch_bounds__(256) void fit_kernel(const float* __restrict__ xh,
                                                  float* __restrict__ loc,
                                                  float* __restrict__ scalef) {
    int gid = blockIdx.x * 256 + threadIdx.x;
    int b = gid >> 7, d = gid & 127;
    const float* p = xh + (size_t)b * 192 * 128 + d;
    float s = 0.f;
    for (int t = 0; t < 192; ++t) s += p[t * 128];
    float m = s * (1.0f / 192.0f);
    float v = 0.f;
    for (int t = 0; t < 192; ++t) {
        float c = p[t * 128] - m; c *= c;
        v = (t == 0) ? c : 0.94f * v + (1.0f - 0.94f) * c;
    }
    loc[gid] = m;
    scalef[gid] = fmaxf(sqrtf(v * 0.5f), 1e-5f);
}

// ---------------- kernel B: per-t embedding -> cond[6][32] ----------------
__global__ __launch_bounds__(256) void temb_kernel(
    const float* __restrict__ w1, const float* __restrict__ b1,
    const float* __restrict__ w2, const float* __restrict__ b2,
    const float* __restrict__ wt, const float* __restrict__ bt,
    float* __restrict__ cond_all, FreqArg fq) {
    int t = blockIdx.x;
    int tid = threadIdx.x;
    __shared__ float pe[128], te1[512], te2[512];
    if (tid < 64) {
        double e = (double)t * fq.f[tid];
        pe[tid]      = (float)sin(e);
        pe[tid + 64] = (float)cos(e);
    }
    __syncthreads();
    for (int j = tid; j < 512; j += 256) {
        float acc = b1[j];
        for (int k = 0; k < 128; ++k) acc += pe[k] * w1[k * 512 + j];
        te1[j] = acc / (1.f + expf(-acc));
    }
    __syncthreads();
    for (int j = tid; j < 512; j += 256) {
        float acc = b2[j];
        for (int k = 0; k < 512; ++k) acc += te1[k] * w2[k * 512 + j];
        te2[j] = acc / (1.f + expf(-acc));
    }
    __syncthreads();
    if (tid < 192) {
        int l = tid >> 5, c = tid & 31;
        float acc = bt[l * 32 + c];
        const float* w = wt + (size_t)l * 512 * 32 + c;
        for (int k = 0; k < 512; ++k) acc += te2[k] * w[k * 32];
        cond_all[t * 192 + tid] = acc;
    }
}

// ---------------- kernel P: pack weights as bf16 A-fragments ----------------
__global__ __launch_bounds__(256) void prep_kernel(
    const float* __restrict__ w_in, const float* __restrict__ lyr_wdil,
    const float* __restrict__ lyr_wout, const float* __restrict__ w_o1,
    const float* __restrict__ w_o2, short* __restrict__ wpack) {
    int gid = blockIdx.x * 256 + threadIdx.x;
    if (gid >= 58368) return;
    int j = gid & 7, l = (gid >> 3) & 63, frag = gid >> 9;
    int m = l & 15, k = (l >> 4) * 8 + j;
    float v;
    if (frag < 8) {
        int m2 = frag >> 2, ks = frag & 3;
        v = w_in[(m2 * 16 + m) * 128 + ks * 32 + k];
    } else if (frag < 80) {
        int fi = frag - 8;
        int li = fi / 12, rem = fi % 12;
        int mg = rem / 6, rem2 = rem % 6;
        int tp = rem2 >> 1, gf = rem2 & 1;
        int o = gf * 32 + mg * 16 + m;
        v = lyr_wdil[((li * 64 + o) * 32 + k) * 3 + tp];
    } else if (frag < 104) {
        int fi = frag - 80;
        int li = fi >> 2, mo = fi & 3;
        v = lyr_wout[li * 2048 + (mo * 16 + m) * 32 + k];
    } else if (frag < 106) {
        int m2 = frag - 104;
        v = w_o1[(m2 * 16 + m) * 32 + k] * INV_SQRT_L;
    } else {
        int m8 = frag - 106;
        v = w_o2[(m8 * 16 + m) * 32 + k];
    }
    wpack[gid] = (short)rne1(v);
}

// conv A-frag loader: base = wpCv + li*12*512; l5 loads only tp==1
__device__ __forceinline__ void load_conv(const short* base, int l, bf16x8* cv, bool l5) {
#pragma unroll
    for (int tp = 0; tp < 3; ++tp) {
        if (l5 && tp != 1) continue;
#pragma unroll
        for (int mg = 0; mg < 2; ++mg)
#pragma unroll
            for (int gf = 0; gf < 2; ++gf)
                cv[tp * 4 + mg * 2 + gf] = ldfrag(base + (mg * 6 + tp * 2 + gf) * 512 + l * 8);
    }
}

// ---------------- kernel C: 50-step diffusion — column-ownership, 2 waves, 6 barriers/step ----------------
// Wave w owns columns w*16..w*16+15 (valid < 24) across ALL channels.
// conv->act->wout->o1->o2->P1 handoffs are same-wave via trB/xbB (wave-private).
// Cross-wave surfaces: hcB side-taps (ping-pong buffers) + condB.
__global__ __launch_bounds__(128, 1) void diffusion_kernel(
    const float* __restrict__ z_init, const float* __restrict__ noise,
    const float* __restrict__ b_in,  const float* __restrict__ lyr_bdil,
    const float* __restrict__ lyr_bout, const float* __restrict__ b_o1,
    const float* __restrict__ b_o2, const float* __restrict__ cond_all,
    const short* __restrict__ wpack, const float* __restrict__ loc,
    const float* __restrict__ scalef, float* __restrict__ out, SchedArg sc) {

    __shared__ __align__(16) short xbB[32 * 136];   // x bf16 [col][128k]; pad cols zero
    __shared__ __align__(16) short hcB[2][33 * 40]; // h+cond ping-pong; col 32 = zeros
    __shared__ __align__(16) short trB[32 * 40];    // wave-private transpose bounce
    __shared__ __align__(16) float biasB[960];
    __shared__ __align__(16) float condB[2][192];

    const int tid = threadIdx.x;
    const int wv  = __builtin_amdgcn_readfirstlane(tid >> 6);   // 0..1
    const int l   = tid & 63;
    const int ln  = l & 15;
    const int lq  = l >> 4;
    const int bb  = blockIdx.x;          // row 0..511
    const int colw = wv * 16 + ln;       // owned column
    const bool cvw = (colw < 24);

    const short* wpP1 = wpack;
    const short* wpCv = wpack + 4096;
    const short* wpWo = wpack + 40960;
    const short* wpO1 = wpack + 53248;
    const short* wpO2 = wpack + 54272;

    // ---- hoisted step-invariant A-frags ----
    bf16x8 aP1[2][4], aWo[6][4], aO1[2], aO2[8];
#pragma unroll
    for (int m = 0; m < 2; ++m) {
#pragma unroll
        for (int ks = 0; ks < 4; ++ks)
            aP1[m][ks] = ldfrag(wpP1 + (m * 4 + ks) * 512 + l * 8);
        aO1[m] = ldfrag(wpO1 + m * 512 + l * 8);
    }
#pragma unroll
    for (int li = 0; li < 6; ++li)
#pragma unroll
        for (int mo = 0; mo < 4; ++mo)
            aWo[li][mo] = ldfrag(wpWo + (li * 4 + mo) * 512 + l * 8);
#pragma unroll
    for (int m8 = 0; m8 < 8; ++m8) aO2[m8] = ldfrag(wpO2 + m8 * 512 + l * 8);

    // conv pipeline registers (ping-pong)
    bf16x8 cvA[12], cvB[12];
    load_conv(wpCv, l, cvA, false);      // layer 0

    // ---- init ----
    for (int i = tid; i < 3072; i += 128) {
        int d = i / 24, h = i - d * 24;
        xbB[h * 136 + d] = (short)rne1(z_init[(size_t)bb * 3072 + i]);
    }
    for (int i = tid; i < 1088; i += 128) xbB[24 * 136 + i] = 0;
    for (int i = tid; i < 960; i += 128) {
        float v;
        if      (i < 32)  v = b_in[i];
        else if (i < 416) v = lyr_bdil[i - 32];
        else if (i < 800) v = lyr_bout[i - 416];
        else if (i < 832) v = b_o1[i - 800];
        else              v = b_o2[i - 832];
        biasB[i] = v;
    }
    for (int i = tid; i < 192; i += 128) condB[0][i] = cond_all[(T_STEPS - 1) * 192 + i];
    if (tid < 40) { hcB[0][32 * 40 + tid] = 0; hcB[1][32 * 40 + tid] = 0; }

    f32x4 xr[8];
#pragma unroll
    for (int m8 = 0; m8 < 8; ++m8) {
        const int d0 = m8 * 16 + lq * 4;
#pragma unroll
        for (int i = 0; i < 4; ++i)
            xr[m8][i] = cvw ? z_init[(size_t)bb * 3072 + (d0 + i) * 24 + colw] : 0.f;
    }
    __syncthreads();

    f32x4 hr[2], skr[2];

// one residual layer: conv (reads hcB[LI&1]) -> act -> (same-wave transpose)
// -> wout (res->hr + hcB[(LI+1)&1], sk->skr). CV = current conv frags;
// prefetches layer NLI into CVN.
#define LAYER(LI, CV, CVN, NLI)                                                          \
    {                                                                                    \
        const int dd = 1 << LI;                                                          \
        f32x4 ac00 = bias4s(biasB + 32 + LI * 64 + lq * 4);        /* mg0 gate */        \
        f32x4 ac01 = bias4s(biasB + 32 + LI * 64 + 32 + lq * 4);   /* mg0 filt */        \
        f32x4 ac10 = bias4s(biasB + 32 + LI * 64 + 16 + lq * 4);   /* mg1 gate */        \
        f32x4 ac11 = bias4s(biasB + 32 + LI * 64 + 48 + lq * 4);   /* mg1 filt */        \
        const short* hb = hcB[LI & 1];                                                   \
        _Pragma("unroll")                                                                \
        for (int tp = 0; tp < 3; ++tp) {                                                 \
            if (LI == 5 && tp != 1) continue;                                            \
            int hh = colw + (tp - 1) * dd;                                               \
            int colp = ((unsigned)hh < 24u) ? hh : 32;                                   \
            bf16x8 b = ldfrag(hb + colp * 40 + lq * 8);                                  \
            ac00 = mma(CV[tp * 4 + 0], b, ac00);                                         \
            ac01 = mma(CV[tp * 4 + 1], b, ac01);                                         \
            ac10 = mma(CV[tp * 4 + 2], b, ac10);                                         \
            ac11 = mma(CV[tp * 4 + 3], b, ac11);                                         \
        }                                                                                \
        load_conv(wpCv + (NLI) * 12 * 512, l, CVN, (NLI) == 5);                          \
        st_bf4(trB + colw * 40 + lq * 4,                                                 \
               fast_tanh(ac01[0]) * fast_sig(ac00[0]),                                   \
               fast_tanh(ac01[1]) * fast_sig(ac00[1]),                                   \
               fast_tanh(ac01[2]) * fast_sig(ac00[2]),                                   \
               fast_tanh(ac01[3]) * fast_sig(ac00[3]));                                  \
        st_bf4(trB + colw * 40 + 16 + lq * 4,                                            \
               fast_tanh(ac11[0]) * fast_sig(ac10[0]),                                   \
               fast_tanh(ac11[1]) * fast_sig(ac10[1]),                                   \
               fast_tanh(ac11[2]) * fast_sig(ac10[2]),                                   \
               fast_tanh(ac11[3]) * fast_sig(ac10[3]));                                  \
        bf16x8 b2 = ldfrag(trB + colw * 40 + lq * 8);                                    \
        if (LI < 5) {                                                                    \
            f32x4 aR0 = mma(aWo[LI][0], b2, bias4s(biasB + 416 + LI * 64 + lq * 4));     \
            f32x4 aR1 = mma(aWo[LI][1], b2, bias4s(biasB + 416 + LI * 64 + 16 + lq * 4));\
            _Pragma("unroll")                                                            \
            for (int i = 0; i < 4; ++i) {                                                \
                hr[0][i] = (hr[0][i] + aR0[i]) * RS2;                                    \
                hr[1][i] = (hr[1][i] + aR1[i]) * RS2;                                    \
            }                                                                            \
            float4 c0 = ld4s(cnd + (LI + 1) * 32 + lq * 4);                              \
            float4 c1 = ld4s(cnd + (LI + 1) * 32 + 16 + lq * 4);                         \
            short* hn = hcB[(LI + 1) & 1];                                               \
            st_bf4(hn + colw * 40 + lq * 4,                                              \
                   hr[0][0] + c0.x, hr[0][1] + c0.y, hr[0][2] + c0.z, hr[0][3] + c0.w);  \
            st_bf4(hn + colw * 40 + 16 + lq * 4,                                         \
                   hr[1][0] + c1.x, hr[1][1] + c1.y, hr[1][2] + c1.z, hr[1][3] + c1.w);  \
        }                                                                                \
        f32x4 aS0 = mma(aWo[LI][2], b2, bias4s(biasB + 416 + LI * 64 + 32 + lq * 4));    \
        f32x4 aS1 = mma(aWo[LI][3], b2, bias4s(biasB + 416 + LI * 64 + 48 + lq * 4));    \
        _Pragma("unroll")                                                                \
        for (int i = 0; i < 4; ++i) { skr[0][i] += aS0[i]; skr[1][i] += aS1[i]; }        \
    }

    for (int step = 0; step < T_STEPS; ++step) {
        const int t = T_STEPS - 1 - step;
        const float* cnd = condB[step & 1];

        // next-step cond: issue loads now, publish at o2
        float cn0 = 0.f, cn1 = 0.f;
        if (step + 1 < T_STEPS) {
            cn0 = cond_all[(t - 1) * 192 + tid];
            if (tid < 64) cn1 = cond_all[(t - 1) * 192 + 128 + tid];
        }

        // ======== P1: h = relu(Win @ x + b_in) -> hr + hcB[0] ========
#pragma unroll
        for (int m = 0; m < 2; ++m) {
            f32x4 acc = bias4s(biasB + m * 16 + lq * 4);
            const short* xb = xbB + colw * 136;
#pragma unroll
            for (int ks = 0; ks < 4; ++ks)
                acc = mma(aP1[m][ks], ldfrag(xb + ks * 32 + lq * 8), acc);
#pragma unroll
            for (int i = 0; i < 4; ++i) { acc[i] = fmaxf(acc[i], 0.f); skr[m][i] = 0.f; }
            hr[m] = acc;
            float4 cv = ld4s(cnd + m * 16 + lq * 4);
            st_bf4(hcB[0] + colw * 40 + m * 16 + lq * 4,
                   acc[0] + cv.x, acc[1] + cv.y, acc[2] + cv.z, acc[3] + cv.w);
        }
        __syncthreads();                     // A: publish hcB[0]

        LAYER(0, cvA, cvB, 1)
        __syncthreads();                     // B: publish hcB[1]
        LAYER(1, cvB, cvA, 2)
        __syncthreads();                     // C
        LAYER(2, cvA, cvB, 3)
        __syncthreads();                     // D
        LAYER(3, cvB, cvA, 4)
        __syncthreads();                     // E
        LAYER(4, cvA, cvB, 5)
        // no barrier: conv5 reads own-column hcB[1] written by wout4 (same wave)
        LAYER(5, cvB, cvA, 0)                // prefetches layer 0 for next step

        // ======== o1: skr -> trB -> B-frag; s = relu(...) -> trB ========
        {
#pragma unroll
            for (int m = 0; m < 2; ++m)
                st_bf4(trB + colw * 40 + m * 16 + lq * 4,
                       skr[m][0], skr[m][1], skr[m][2], skr[m][3]);
            bf16x8 b = ldfrag(trB + colw * 40 + lq * 8);
#pragma unroll
            for (int m = 0; m < 2; ++m) {
                f32x4 acc = mma(aO1[m], b, bias4s(biasB + 800 + m * 16 + lq * 4));
                st_bf4(trB + colw * 40 + m * 16 + lq * 4,
                       fmaxf(acc[0], 0.f), fmaxf(acc[1], 0.f),
                       fmaxf(acc[2], 0.f), fmaxf(acc[3], 0.f));
            }
        }

        // ======== o2: eps + fused DDPM x-update (regs) -> xbB; publish cond ========
        {
            bf16x8 b = ldfrag(trB + colw * 40 + lq * 8);
            const float cx0 = sc.cx0[t], cxt = sc.cxt[t], sig = sc.sig[t];
            const float s1m = sc.s1m[t], isab = sc.isab[t];
            const float* nzp = noise + ((size_t)step * NB + bb) * 3072 + (cvw ? colw : 0);
#pragma unroll
            for (int m8 = 0; m8 < 8; ++m8) {
                const int d0 = m8 * 16 + lq * 4;
                f32x4 acc = mma(aO2[m8], b, bias4s(biasB + 832 + d0));
                if (cvw) {
                    float xn[4];
#pragma unroll
                    for (int i = 0; i < 4; ++i) {
                        float xv = xr[m8][i];
                        float nz = nzp[(d0 + i) * 24];
                        float x0 = fminf(fmaxf((xv - s1m * acc[i]) * isab, -1.f), 1.f);
                        xn[i] = cx0 * x0 + cxt * xv + sig * nz;
                        xr[m8][i] = xn[i];
                    }
                    st_bf4(xbB + colw * 136 + d0, xn[0], xn[1], xn[2], xn[3]);
                }
            }
            if (step + 1 < T_STEPS) {
                condB[(step + 1) & 1][tid] = cn0;
                if (tid < 64) condB[(step + 1) & 1][128 + tid] = cn1;
            }
        }
        __syncthreads();                     // G: publish condB (+ step boundary)
    }
#undef LAYER

    // ---- epilogue: Gaussian -> Student-t4 from registers, direct stores ----
    if (cvw) {
        const int b = bb & 31;
#pragma unroll
        for (int m8 = 0; m8 < 8; ++m8) {
            const int d0 = m8 * 16 + lq * 4;
            float4 l4 = ld4g(loc + b * 128 + d0);
            float4 s4 = ld4g(scalef + b * 128 + d0);
            float4 o4;
#pragma unroll
            for (int e = 0; e < 4; ++e) {
                float z = xr[m8][e];
                float u = 0.5f * (1.f + erff(z * RS2));
                u = fminf(fmaxf(u, 1e-6f), 1.f - 1e-6f);
                float a4 = fminf(fmaxf(4.f * u * (1.f - u), 1e-12f), 1.f);
                float rr = sqrtf(a4);
                float q2 = 2.f * sqrtf(fmaxf(cosf(acosf(rr) * (1.f / 3.f)) / rr - 1.f, 0.f));
                float tstd = (u < 0.5f) ? -q2 : q2;
                (&o4.x)[e] = (&l4.x)[e] + (&s4.x)[e] * tstd;
            }
            *reinterpret_cast<float4*>(out + (size_t)bb * 3072 + colw * 128 + d0) = o4;
        }
    }
}

// ---------------- host ----------------
extern "C" void kernel_launch(void* const* d_in, const int* in_sizes, int n_in,
                              void* d_out, int out_size, void* d_ws, size_t ws_size,
                              hipStream_t stream) {
    const float* x_hist  = (const float*)d_in[0];
    const float* z_init  = (const float*)d_in[1];
    const float* noise   = (const float*)d_in[2];
    const float* w_in    = (const float*)d_in[3];
    const float* b_in    = (const float*)d_in[4];
    const float* temb_w1 = (const float*)d_in[5];
    const float* temb_b1 = (const float*)d_in[6];
    const float* temb_w2 = (const float*)d_in[7];
    const float* temb_b2 = (const float*)d_in[8];
    const float* lyr_wt  = (const float*)d_in[9];
    const float* lyr_bt  = (const float*)d_in[10];
    const float* lyr_wdil= (const float*)d_in[11];
    const float* lyr_bdil= (const float*)d_in[12];
    const float* lyr_wout= (const float*)d_in[13];
    const float* lyr_bout= (const float*)d_in[14];
    const float* w_o1    = (const float*)d_in[15];
    const float* b_o1    = (const float*)d_in[16];
    const float* w_o2    = (const float*)d_in[17];
    const float* b_o2    = (const float*)d_in[18];
    float* out = (float*)d_out;

    float* loc      = (float*)d_ws;                     // 4096 f32
    float* scalef   = loc + 4096;                       // 4096 f32
    float* cond_all = scalef + 4096;                    // 9600 f32
    short* wpack    = (short*)d_ws + WPACK_SHORT_OFF;   // 58368 bf16

    SchedArg sa;
    double abar = 1.0;
    for (int t = 0; t < T_STEPS; ++t) {
        double beta  = 1e-4 + (0.1 - 1e-4) * ((double)t / 49.0);
        double alpha = 1.0 - beta;
        double abprev = abar;
        abar *= alpha;
        sa.cx0[t]  = (float)(beta * sqrt(abprev) / (1.0 - abar));
        sa.cxt[t]  = (float)((1.0 - abprev) * sqrt(alpha) / (1.0 - abar));
        double pv  = beta * (1.0 - abprev) / (1.0 - abar);
        sa.sig[t]  = (t > 0) ? (float)sqrt(pv) : 0.f;
        sa.s1m[t]  = (float)sqrt(1.0 - abar);
        sa.isab[t] = (float)(1.0 / sqrt(abar));
    }
    FreqArg fa;
    for (int j = 0; j < 64; ++j) fa.f[j] = pow(10.0, (double)j * 4.0 / 63.0);

    prep_kernel<<<228, 256, 0, stream>>>(w_in, lyr_wdil, lyr_wout, w_o1, w_o2, wpack);
    fit_kernel<<<16, 256, 0, stream>>>(x_hist, loc, scalef);
    temb_kernel<<<T_STEPS, 256, 0, stream>>>(temb_w1, temb_b1, temb_w2, temb_b2,
                                             lyr_wt, lyr_bt, cond_all, fa);
    diffusion_kernel<<<NB, 128, 0, stream>>>(z_init, noise, b_in, lyr_bdil,
                                             lyr_bout, b_o1, b_o2, cond_all,
                                             wpack, loc, scalef, out, sa);
}

// Round 14
// 483.540 us; speedup vs baseline: 1.4871x; 1.3937x over previous
//
#include <hip/hip_runtime.h>
#include <math.h>

// ---------------- constants ----------------
#define T_STEPS 50
#define NB 512
#define RS2 0.70710678118654752f
#define INV_SQRT_L 0.40824829046386302f
#define WPACK_SHORT_OFF 36864    // d_ws offset in shorts (= float off 18432)

struct SchedArg { float cx0[T_STEPS], cxt[T_STEPS], sig[T_STEPS], s1m[T_STEPS], isab[T_STEPS]; };
struct FreqArg  { double f[64]; };

typedef short bf16x8 __attribute__((ext_vector_type(8)));
typedef float f32x4  __attribute__((ext_vector_type(4)));

__device__ __forceinline__ float4 ld4s(const float* p) { return *reinterpret_cast<const float4*>(p); }
__device__ __forceinline__ float4 ld4g(const float* __restrict__ p) { return *reinterpret_cast<const float4*>(p); }
__device__ __forceinline__ float fast_sig(float x)  { return 1.f / (1.f + __expf(-x)); }
__device__ __forceinline__ float fast_tanh(float x) { float e = __expf(2.f * x); return 1.f - 2.f / (e + 1.f); }

// f32 -> bf16 (RNE). Prep kernel uses the manual version; hot path uses HW packer.
__device__ __forceinline__ unsigned rne1(float f) {
    unsigned u = __float_as_uint(f);
    return (u + 0x7FFFu + ((u >> 16) & 1u)) >> 16;
}
__device__ __forceinline__ unsigned pk2(float a, float b) {   // lo=bf16(a), hi=bf16(b)
    unsigned r;
    asm("v_cvt_pk_bf16_f32 %0, %1, %2" : "=v"(r) : "v"(a), "v"(b));
    return r;
}
__device__ __forceinline__ void st_bf4(short* p, float a, float b, float c, float d) {
    uint2 v; v.x = pk2(a, b); v.y = pk2(c, d);
    *reinterpret_cast<uint2*>(p) = v;
}
__device__ __forceinline__ f32x4 mma(bf16x8 a, bf16x8 b, f32x4 c) {
    return __builtin_amdgcn_mfma_f32_16x16x32_bf16(a, b, c, 0, 0, 0);
}
__device__ __forceinline__ f32x4 bias4s(const float* p) {
    float4 b = ld4s(p);
    f32x4 r; r[0] = b.x; r[1] = b.y; r[2] = b.z; r[3] = b.w;
    return r;
}
__device__ __forceinline__ bf16x8 ldfrag(const short* p) {
    return *reinterpret_cast<const bf16x8*>(p);
}

// ---------------- kernel A: Student-t marginal fit ----------------
__global__ __launch_bounds__(256) void fit_kernel(const float* __restrict__ xh,
                                                  float* __restrict__ loc,
                                                  float* __restrict__ scalef) {
    int gid = blockIdx.x * 256 + threadIdx.x;
    int b = gid >> 7, d = gid & 127;
    const float* p = xh + (size_t)b * 192 * 128 + d;
    float s = 0.f;
    for (int t = 0; t < 192; ++t) s += p[t * 128];
    float m = s * (1.0f / 192.0f);
    float v = 0.f;
    for (int t = 0; t < 192; ++t) {
        float c = p[t * 128] - m; c *= c;
        v = (t == 0) ? c : 0.94f * v + (1.0f - 0.94f) * c;
    }
    loc[gid] = m;
    scalef[gid] = fmaxf(sqrtf(v * 0.5f), 1e-5f);
}

// ---------------- kernel B: per-t embedding -> cond[6][32] ----------------
__global__ __launch_bounds__(256) void temb_kernel(
    const float* __restrict__ w1, const float* __restrict__ b1,
    const float* __restrict__ w2, const float* __restrict__ b2,
    const float* __restrict__ wt, const float* __restrict__ bt,
    float* __restrict__ cond_all, FreqArg fq) {
    int t = blockIdx.x;
    int tid = threadIdx.x;
    __shared__ float pe[128], te1[512], te2[512];
    if (tid < 64) {
        double e = (double)t * fq.f[tid];
        pe[tid]      = (float)sin(e);
        pe[tid + 64] = (float)cos(e);
    }
    __syncthreads();
    for (int j = tid; j < 512; j += 256) {
        float acc = b1[j];
        for (int k = 0; k < 128; ++k) acc += pe[k] * w1[k * 512 + j];
        te1[j] = acc / (1.f + expf(-acc));
    }
    __syncthreads();
    for (int j = tid; j < 512; j += 256) {
        float acc = b2[j];
        for (int k = 0; k < 512; ++k) acc += te1[k] * w2[k * 512 + j];
        te2[j] = acc / (1.f + expf(-acc));
    }
    __syncthreads();
    if (tid < 192) {
        int l = tid >> 5, c = tid & 31;
        float acc = bt[l * 32 + c];
        const float* w = wt + (size_t)l * 512 * 32 + c;
        for (int k = 0; k < 512; ++k) acc += te2[k] * w[k * 32];
        cond_all[t * 192 + tid] = acc;
    }
}

// ---------------- kernel P: pack weights as bf16 A-fragments ----------------
// A-frag layout (v_mfma_f32_16x16x32_bf16): lane l elem j holds A[m=l&15][k=(l>>4)*8+j].
__global__ __launch_bounds__(256) void prep_kernel(
    const float* __restrict__ w_in, const float* __restrict__ lyr_wdil,
    const float* __restrict__ lyr_wout, const float* __restrict__ w_o1,
    const float* __restrict__ w_o2, short* __restrict__ wpack) {
    int gid = blockIdx.x * 256 + threadIdx.x;
    if (gid >= 58368) return;
    int j = gid & 7, l = (gid >> 3) & 63, frag = gid >> 9;
    int m = l & 15, k = (l >> 4) * 8 + j;
    float v;
    if (frag < 8) {
        int m2 = frag >> 2, ks = frag & 3;
        v = w_in[(m2 * 16 + m) * 128 + ks * 32 + k];
    } else if (frag < 80) {
        int fi = frag - 8;
        int li = fi / 12, rem = fi % 12;
        int mg = rem / 6, rem2 = rem % 6;
        int tp = rem2 >> 1, gf = rem2 & 1;
        int o = gf * 32 + mg * 16 + m;
        v = lyr_wdil[((li * 64 + o) * 32 + k) * 3 + tp];
    } else if (frag < 104) {
        int fi = frag - 80;
        int li = fi >> 2, mo = fi & 3;
        v = lyr_wout[li * 2048 + (mo * 16 + m) * 32 + k];
    } else if (frag < 106) {
        int m2 = frag - 104;
        v = w_o1[(m2 * 16 + m) * 32 + k] * INV_SQRT_L;
    } else {
        int m8 = frag - 106;
        v = w_o2[(m8 * 16 + m) * 32 + k];
    }
    wpack[gid] = (short)rne1(v);
}

// ---------------- kernel C: 50-step diffusion (MFMA), 1 row/block, 4 waves ----------------
// h/skip/x state in registers (wave re-tiling: wave w owns res (mo=w>>1,n=w&1),
// sk (ms=w>>1,n=w&1), matching its P1/conv/o1 tiles). LDS holds only the
// cross-wave bounce buffers. bf16 packing via v_cvt_pk_bf16_f32.
__global__ __launch_bounds__(256, 2) void diffusion_kernel(
    const float* __restrict__ z_init, const float* __restrict__ noise,
    const float* __restrict__ b_in,  const float* __restrict__ lyr_bdil,
    const float* __restrict__ lyr_bout, const float* __restrict__ b_o1,
    const float* __restrict__ b_o2, const float* __restrict__ cond_all,
    const short* __restrict__ wpack, const float* __restrict__ loc,
    const float* __restrict__ scalef, float* __restrict__ out, SchedArg sc) {

    __shared__ __align__(16) short xbB[32 * 136];   // x bf16 [col][128k]; cols 24..31 zero
    __shared__ __align__(16) short hcB[33 * 40];    // h+cond; col 32 = zeros
    __shared__ __align__(16) short actB[32 * 40];   // conv act / s
    __shared__ __align__(16) short skB[32 * 40];    // skip publish buffer
    __shared__ __align__(16) float biasB[960];      // b_in|bdil|bout|b_o1|b_o2
    __shared__ __align__(16) float condB[2][192];   // double-buffered cond[t]

    const int tid = threadIdx.x;
    const int wv  = __builtin_amdgcn_readfirstlane(tid >> 6);   // 0..3
    const int l   = tid & 63;
    const int ln  = l & 15;
    const int lq  = l >> 4;
    const int bb  = blockIdx.x;          // row 0..511

    const short* wpP1 = wpack;
    const short* wpCv = wpack + 4096;
    const short* wpWo = wpack + 40960;
    const short* wpO1 = wpack + 53248;
    const short* wpO2 = wpack + 54272;

    const int mh   = wv >> 1;            // m-tile for P1/conv/res/sk/o1
    const int nn   = wv & 1;             // n-tile
    const int colw = nn * 16 + ln;       // 0..31 (valid h < 24)
    const bool cvw = (colw < 24);

    // ---- hoisted step-invariant A-frags ----
    bf16x8 aP1[4], aCv[6][3][2], aO1, aWoR[5], aWoS[6], aO2[2];
#pragma unroll
    for (int ks = 0; ks < 4; ++ks)
        aP1[ks] = ldfrag(wpP1 + (mh * 4 + ks) * 512 + l * 8);
    aO1 = ldfrag(wpO1 + mh * 512 + l * 8);
#pragma unroll
    for (int li = 0; li < 6; ++li) {
#pragma unroll
        for (int tp = 0; tp < 3; ++tp) {
            if (li == 5 && tp != 1) continue;
#pragma unroll
            for (int gf = 0; gf < 2; ++gf)
                aCv[li][tp][gf] = ldfrag(wpCv + (li * 12 + mh * 6 + tp * 2 + gf) * 512 + l * 8);
        }
        if (li < 5) aWoR[li] = ldfrag(wpWo + (li * 4 + mh) * 512 + l * 8);
        aWoS[li] = ldfrag(wpWo + (li * 4 + 2 + mh) * 512 + l * 8);
    }
    aO2[0] = ldfrag(wpO2 + wv * 512 + l * 8);
    aO2[1] = ldfrag(wpO2 + (wv + 4) * 512 + l * 8);

    // ---- init LDS + x registers ----
    for (int i = tid; i < 3072; i += 256) {
        int d = i / 24, h = i - d * 24;
        xbB[h * 136 + d] = (short)rne1(z_init[(size_t)bb * 3072 + i]);
    }
    for (int i = tid; i < 1088; i += 256) xbB[24 * 136 + i] = 0;       // pad cols zero
    for (int i = tid; i < 960; i += 256) {
        float v;
        if      (i < 32)  v = b_in[i];
        else if (i < 416) v = lyr_bdil[i - 32];
        else if (i < 800) v = lyr_bout[i - 416];
        else if (i < 832) v = b_o1[i - 800];
        else              v = b_o2[i - 832];
        biasB[i] = v;
    }
    if (tid < 192) condB[0][tid] = cond_all[(T_STEPS - 1) * 192 + tid];
    if (tid < 40) hcB[32 * 40 + tid] = 0;

    f32x4 xr[2][2];                      // [mi][n] : d0=(wv+4mi)*16+lq*4, col=n*16+ln
#pragma unroll
    for (int mi = 0; mi < 2; ++mi)
#pragma unroll
        for (int n = 0; n < 2; ++n) {
            const int col = n * 16 + ln;
            const int d0 = (wv + 4 * mi) * 16 + lq * 4;
#pragma unroll
            for (int i = 0; i < 4; ++i)
                xr[mi][n][i] = (col < 24) ? z_init[(size_t)bb * 3072 + (d0 + i) * 24 + col] : 0.f;
        }
    __syncthreads();

    for (int step = 0; step < T_STEPS; ++step) {
        const int t = T_STEPS - 1 - step;
        const float* cnd = condB[step & 1];

        // next-step cond: issue load now, publish at o2
        float cndnext = 0.f;
        if (step + 1 < T_STEPS && tid < 192)
            cndnext = cond_all[(t - 1) * 192 + tid];

        // ======== P1: h = relu(Win @ x + b_in) -> hr (regs) + hcB ========
        f32x4 hr;
        {
            f32x4 acc = bias4s(biasB + mh * 16 + lq * 4);
            const short* xb = xbB + colw * 136;
#pragma unroll
            for (int ks = 0; ks < 4; ++ks)
                acc = mma(aP1[ks], ldfrag(xb + ks * 32 + lq * 8), acc);
#pragma unroll
            for (int i = 0; i < 4; ++i) acc[i] = fmaxf(acc[i], 0.f);
            hr = acc;
            float4 cv = ld4s(cnd + mh * 16 + lq * 4);
            st_bf4(hcB + colw * 40 + mh * 16 + lq * 4,
                   hr[0] + cv.x, hr[1] + cv.y, hr[2] + cv.z, hr[3] + cv.w);
        }
        f32x4 skr;
#pragma unroll
        for (int i = 0; i < 4; ++i) skr[i] = 0.f;
        __syncthreads();

        // ======== 6 residual layers ========
#pragma unroll
        for (int li = 0; li < 6; ++li) {
            const int dd = 1 << li;
            // ---- conv (shifted K=32 GEMMs) + gated act -> actB ----
            {
                f32x4 accg = bias4s(biasB + 32 + li * 64 + mh * 16 + lq * 4);
                f32x4 accf = bias4s(biasB + 32 + li * 64 + 32 + mh * 16 + lq * 4);
#pragma unroll
                for (int tp = 0; tp < 3; ++tp) {
                    if (li == 5 && tp != 1) continue;
                    int hh = colw + (tp - 1) * dd;
                    int colp = ((unsigned)hh < 24u) ? hh : 32;
                    bf16x8 b = ldfrag(hcB + colp * 40 + lq * 8);
                    accg = mma(aCv[li][tp][0], b, accg);
                    accf = mma(aCv[li][tp][1], b, accf);
                }
                st_bf4(actB + colw * 40 + mh * 16 + lq * 4,
                       fast_tanh(accf[0]) * fast_sig(accg[0]),
                       fast_tanh(accf[1]) * fast_sig(accg[1]),
                       fast_tanh(accf[2]) * fast_sig(accg[2]),
                       fast_tanh(accf[3]) * fast_sig(accg[3]));
            }
            __syncthreads();

            // ---- wout: res -> hr (regs) + hcB; sk -> skr (regs); publish skB at l5 ----
            {
                bf16x8 b = ldfrag(actB + colw * 40 + lq * 8);
                if (li < 5) {
                    f32x4 accR = mma(aWoR[li], b,
                                     bias4s(biasB + 416 + li * 64 + mh * 16 + lq * 4));
#pragma unroll
                    for (int i = 0; i < 4; ++i) hr[i] = (hr[i] + accR[i]) * RS2;
                    float4 cv = ld4s(cnd + (li + 1) * 32 + mh * 16 + lq * 4);
                    st_bf4(hcB + colw * 40 + mh * 16 + lq * 4,
                           hr[0] + cv.x, hr[1] + cv.y, hr[2] + cv.z, hr[3] + cv.w);
                }
                f32x4 accS = mma(aWoS[li], b,
                                 bias4s(biasB + 416 + li * 64 + (2 + mh) * 16 + lq * 4));
#pragma unroll
                for (int i = 0; i < 4; ++i) skr[i] += accS[i];
                if (li == 5)
                    st_bf4(skB + colw * 40 + mh * 16 + lq * 4,
                           skr[0], skr[1], skr[2], skr[3]);
            }
            __syncthreads();
        }

        // ======== o1: s = relu(b_o1 + Wo1s @ skip) -> actB ========
        {
            f32x4 acc = bias4s(biasB + 800 + mh * 16 + lq * 4);
            acc = mma(aO1, ldfrag(skB + colw * 40 + lq * 8), acc);
            st_bf4(actB + colw * 40 + mh * 16 + lq * 4,
                   fmaxf(acc[0], 0.f), fmaxf(acc[1], 0.f),
                   fmaxf(acc[2], 0.f), fmaxf(acc[3], 0.f));
        }
        __syncthreads();

        // ======== o2: eps + fused DDPM x-update (regs); publish cond ========
        {
            const float cx0 = sc.cx0[t], cxt = sc.cxt[t], sig = sc.sig[t];
            const float s1m = sc.s1m[t], isab = sc.isab[t];
#pragma unroll
            for (int mi = 0; mi < 2; ++mi) {
                const int d0 = (wv + 4 * mi) * 16 + lq * 4;
                f32x4 bia = bias4s(biasB + 832 + d0);
#pragma unroll
                for (int n = 0; n < 2; ++n) {
                    const int col = n * 16 + ln;
                    f32x4 acc = mma(aO2[mi], ldfrag(actB + col * 40 + lq * 8), bia);
                    if (col < 24) {
                        const float* nzp = noise + ((size_t)step * NB + bb) * 3072 + col;
                        float xn[4];
#pragma unroll
                        for (int i = 0; i < 4; ++i) {
                            float xv = xr[mi][n][i];
                            float nz = nzp[(d0 + i) * 24];
                            float x0 = fminf(fmaxf((xv - s1m * acc[i]) * isab, -1.f), 1.f);
                            xn[i] = cx0 * x0 + cxt * xv + sig * nz;
                            xr[mi][n][i] = xn[i];
                        }
                        st_bf4(xbB + col * 136 + d0, xn[0], xn[1], xn[2], xn[3]);
                    }
                }
            }
            if (step + 1 < T_STEPS && tid < 192)
                condB[(step + 1) & 1][tid] = cndnext;
        }
        __syncthreads();
    }

    // ---- epilogue: Gaussian -> Student-t4 from registers, direct stores ----
    {
        const int b = bb & 31;
#pragma unroll
        for (int mi = 0; mi < 2; ++mi) {
#pragma unroll
            for (int n = 0; n < 2; ++n) {
                const int col = n * 16 + ln;
                if (col >= 24) continue;
                const int d0 = (wv + 4 * mi) * 16 + lq * 4;
                float4 l4 = ld4g(loc + b * 128 + d0);
                float4 s4 = ld4g(scalef + b * 128 + d0);
                float4 o4;
#pragma unroll
                for (int e = 0; e < 4; ++e) {
                    float z = xr[mi][n][e];
                    float u = 0.5f * (1.f + erff(z * RS2));
                    u = fminf(fmaxf(u, 1e-6f), 1.f - 1e-6f);
                    float a4 = fminf(fmaxf(4.f * u * (1.f - u), 1e-12f), 1.f);
                    float rr = sqrtf(a4);
                    float q2 = 2.f * sqrtf(fmaxf(cosf(acosf(rr) * (1.f / 3.f)) / rr - 1.f, 0.f));
                    float tstd = (u < 0.5f) ? -q2 : q2;
                    (&o4.x)[e] = (&l4.x)[e] + (&s4.x)[e] * tstd;
                }
                *reinterpret_cast<float4*>(out + (size_t)bb * 3072 + col * 128 + d0) = o4;
            }
        }
    }
}

// ---------------- host ----------------
extern "C" void kernel_launch(void* const* d_in, const int* in_sizes, int n_in,
                              void* d_out, int out_size, void* d_ws, size_t ws_size,
                              hipStream_t stream) {
    const float* x_hist  = (const float*)d_in[0];
    const float* z_init  = (const float*)d_in[1];
    const float* noise   = (const float*)d_in[2];
    const float* w_in    = (const float*)d_in[3];
    const float* b_in    = (const float*)d_in[4];
    const float* temb_w1 = (const float*)d_in[5];
    const float* temb_b1 = (const float*)d_in[6];
    const float* temb_w2 = (const float*)d_in[7];
    const float* temb_b2 = (const float*)d_in[8];
    const float* lyr_wt  = (const float*)d_in[9];
    const float* lyr_bt  = (const float*)d_in[10];
    const float* lyr_wdil= (const float*)d_in[11];
    const float* lyr_bdil= (const float*)d_in[12];
    const float* lyr_wout= (const float*)d_in[13];
    const float* lyr_bout= (const float*)d_in[14];
    const float* w_o1    = (const float*)d_in[15];
    const float* b_o1    = (const float*)d_in[16];
    const float* w_o2    = (const float*)d_in[17];
    const float* b_o2    = (const float*)d_in[18];
    float* out = (float*)d_out;

    float* loc      = (float*)d_ws;                     // 4096 f32
    float* scalef   = loc + 4096;                       // 4096 f32
    float* cond_all = scalef + 4096;                    // 9600 f32
    short* wpack    = (short*)d_ws + WPACK_SHORT_OFF;   // 58368 bf16

    SchedArg sa;
    double abar = 1.0;
    for (int t = 0; t < T_STEPS; ++t) {
        double beta  = 1e-4 + (0.1 - 1e-4) * ((double)t / 49.0);
        double alpha = 1.0 - beta;
        double abprev = abar;
        abar *= alpha;
        sa.cx0[t]  = (float)(beta * sqrt(abprev) / (1.0 - abar));
        sa.cxt[t]  = (float)((1.0 - abprev) * sqrt(alpha) / (1.0 - abar));
        double pv  = beta * (1.0 - abprev) / (1.0 - abar);
        sa.sig[t]  = (t > 0) ? (float)sqrt(pv) : 0.f;
        sa.s1m[t]  = (float)sqrt(1.0 - abar);
        sa.isab[t] = (float)(1.0 / sqrt(abar));
    }
    FreqArg fa;
    for (int j = 0; j < 64; ++j) fa.f[j] = pow(10.0, (double)j * 4.0 / 63.0);

    prep_kernel<<<228, 256, 0, stream>>>(w_in, lyr_wdil, lyr_wout, w_o1, w_o2, wpack);
    fit_kernel<<<16, 256, 0, stream>>>(x_hist, loc, scalef);
    temb_kernel<<<T_STEPS, 256, 0, stream>>>(temb_w1, temb_b1, temb_w2, temb_b2,
                                             lyr_wt, lyr_bt, cond_all, fa);
    diffusion_kernel<<<NB, 256, 0, stream>>>(z_init, noise, b_in, lyr_bdil,
                                             lyr_bout, b_o1, b_o2, cond_all,
                                             wpack, loc, scalef, out, sa);
}